// Round 3
// baseline (344.712 us; speedup 1.0000x reference)
//
#include <hip/hip_runtime.h>

typedef _Float16 f16;
typedef _Float16 f16x4 __attribute__((ext_vector_type(4)));
typedef _Float16 f16x8 __attribute__((ext_vector_type(8)));
typedef float f32x4 __attribute__((ext_vector_type(4)));

// ---- f16 weight arena layout in d_ws (units: halfs) ----
#define OFF_W1  0            // s1_w *30   [128][64]
#define OFF_W2  8192         // s2_w *30   [256][128]
#define OFF_WF1 40960        // fc1_w      [64][256]
#define OFF_WF2 57344        // fc2_w      [64][64]
#define OFF_WF3 61440        // fc3_w      [256][64]
#define OFF_WGE 77824        // [16][288]: rows 0..6 gate_w, 8..14 exp_w (cols<256), rest 0
#define OFF_WP2 82432        // p2_w *30   [32][32]
#define TOTH    83456
// ---- fp32 bias arena at (float*)(ws + TOTH), units: floats ----
#define FB_B1  0             // 30*s1_b (128)
#define FB_B2  128           // 30*s2_b (256)
#define FB_F1  384           // fc1_b (64)
#define FB_F2  448           // fc2_b (64)
#define FB_F3  512           // fc3_b (256)
#define FB_GE  768           // gate_b(0..6), 0, exp_b(8..14), 0
#define FB_P2  784           // 30*p2_b (32)

__device__ __forceinline__ float sin_rev(float r){
#if __has_builtin(__builtin_amdgcn_sinf)
  return __builtin_amdgcn_sinf(r);     // v_sin_f32: input in revolutions
#else
  return __sinf(r * 6.283185307179586f);
#endif
}
__device__ __forceinline__ float fsin(float x){
  float r = x * 0.15915494309189535f;  // 1/(2pi)
  r -= rintf(r);                       // reduce to [-0.5, 0.5] rev
  return sin_rev(r);
}
__device__ __forceinline__ float fcos(float x){
  float r = x * 0.15915494309189535f + 0.25f;  // cos(x) = sin(x + pi/2)
  r -= rintf(r);
  return sin_rev(r);
}

// ---------- weight conversion: fp32 -> f16, OMEGA folded ----------
__global__ void convert_w(const float* __restrict__ s1w, const float* __restrict__ s1b,
                          const float* __restrict__ s2w, const float* __restrict__ s2b,
                          const float* __restrict__ f1w, const float* __restrict__ f1b,
                          const float* __restrict__ f2w, const float* __restrict__ f2b,
                          const float* __restrict__ f3w, const float* __restrict__ f3b,
                          const float* __restrict__ gw,  const float* __restrict__ gb,
                          const float* __restrict__ ew,  const float* __restrict__ eb,
                          const float* __restrict__ p2w, const float* __restrict__ p2b,
                          f16* __restrict__ ws)
{
  int stride = gridDim.x * blockDim.x;
  int tid0 = blockIdx.x * blockDim.x + threadIdx.x;
  for (int i = tid0; i < TOTH; i += stride){
    float v;
    if (i < OFF_W2)       v = 30.0f * s1w[i];
    else if (i < OFF_WF1) v = 30.0f * s2w[i - OFF_W2];
    else if (i < OFF_WF2) v = f1w[i - OFF_WF1];
    else if (i < OFF_WF3) v = f2w[i - OFF_WF2];
    else if (i < OFF_WGE) v = f3w[i - OFF_WF3];
    else if (i < OFF_WP2){
      int j = i - OFF_WGE; int row = j / 288; int col = j - row * 288;
      v = (row < 7) ? gw[row * 288 + col]
        : ((row >= 8 && row < 15 && col < 256) ? ew[(row - 8) * 256 + col] : 0.0f);
    }
    else v = 30.0f * p2w[i - OFF_WP2];
    ws[i] = (f16)v;
  }
  float* bws = (float*)(ws + TOTH);
  for (int i = tid0; i < 816; i += stride){
    float v;
    if (i < 128)      v = 30.0f * s1b[i];
    else if (i < 384) v = 30.0f * s2b[i - 128];
    else if (i < 448) v = f1b[i - 384];
    else if (i < 512) v = f2b[i - 448];
    else if (i < 768) v = f3b[i - 512];
    else if (i < 784){ int j = i - 768;
      v = (j < 7) ? gb[j] : ((j >= 8 && j < 15) ? eb[j - 8] : 0.0f); }
    else v = 30.0f * p2b[i - 784];
    bws[i] = v;
  }
}

// Swapped-operand layer pass: D = W @ act^T  ->  acc[i] = (batch row r = l15+rt*16,
// neuron n = ct*16 + lk*4 + i).  Fully unrolled (compile-time trips), A-frags
// (activations) hoisted across the whole layer. Epilogue sees r, n0, v0..v3.
#define MM_LAYER(K_, CT_, ACT_, SA_, WOFF_, BOFF_, ...)                            \
  {                                                                                \
    f16x8 af[2][(K_) / 32];                                                        \
    _Pragma("unroll")                                                              \
    for (int rt = 0; rt < 2; ++rt)                                                 \
      _Pragma("unroll")                                                            \
      for (int ks = 0; ks < (K_) / 32; ++ks)                                       \
        af[rt][ks] = *(const f16x8*)((ACT_) + (rt * 16 + l15) * (SA_) + ks * 32 + kb); \
    _Pragma("unroll")                                                              \
    for (int j = 0; j < (CT_) / 4; ++j){                                           \
      const int ct = wid + j * 4;                                                  \
      float4 bias = *(const float4*)(bws + (BOFF_) + ct * 16 + lk * 4);            \
      f32x4 acc0 = {0.f, 0.f, 0.f, 0.f}, acc1 = {0.f, 0.f, 0.f, 0.f};              \
      _Pragma("unroll")                                                            \
      for (int ks = 0; ks < (K_) / 32; ++ks){                                      \
        f16x8 w = *(const f16x8*)(ws + (WOFF_) + (ct * 16 + l15) * (K_) + ks * 32 + kb); \
        acc0 = __builtin_amdgcn_mfma_f32_16x16x32_f16(w, af[0][ks], acc0, 0, 0, 0); \
        acc1 = __builtin_amdgcn_mfma_f32_16x16x32_f16(w, af[1][ks], acc1, 0, 0, 0); \
      }                                                                            \
      _Pragma("unroll")                                                            \
      for (int rt = 0; rt < 2; ++rt){                                              \
        f32x4 acc = rt ? acc1 : acc0;                                              \
        const int r = rt * 16 + l15;                                               \
        const int n0 = ct * 16 + lk * 4;                                           \
        float v0 = acc[0] + bias.x, v1 = acc[1] + bias.y,                          \
              v2 = acc[2] + bias.z, v3 = acc[3] + bias.w;                          \
        __VA_ARGS__;                                                               \
      }                                                                            \
    }                                                                              \
  }                                                                                \
  __syncthreads();

#define STORE4(P_, S_, E0_, E1_, E2_, E3_)                                         \
  { f16x4 o; o[0] = (f16)(E0_); o[1] = (f16)(E1_); o[2] = (f16)(E2_); o[3] = (f16)(E3_); \
    *(f16x4*)((P_) + r * (S_) + n0) = o; }

__global__ __launch_bounds__(256, 4) void moe_main(
    const float* __restrict__ x,
    const float* __restrict__ pe_w, const float* __restrict__ pe_b,
    const float* __restrict__ p1_w, const float* __restrict__ p1_b,
    const f16* __restrict__ ws, float* __restrict__ out)
{
  const float* bws = (const float*)(ws + TOTH);
  __shared__ __align__(16) unsigned char smem[32768];
  f16* h0 = (f16*)smem;                 // [32][72]  PE out; overlay t1 [32][72]
  f16* t1 = (f16*)smem;
  f16* h1 = (f16*)(smem + 4608);        // [32][136] s1 out; overlay t2 [32][72]
  f16* t2 = (f16*)(smem + 4608);
  f16* h2 = (f16*)(smem + 13312);       // [32][264] s2 out; fc3 in-place; f1 overlay
  f16* f1 = (f16*)(smem + 13312);       // [32][40]  policy layer-1 (dead before s2)
  f16* f2 = (f16*)(smem + 30208);       // [32][40]  policy layer-2 out

  const int tid = threadIdx.x;
  const int lane = tid & 63, wid = tid >> 6;
  const int l15 = lane & 15, lk = lane >> 4, kb = lk * 8;
  const long long base = (long long)blockIdx.x * 32;

  { // positional encoding (sin/cos) + policy layer 1  (fp32 VALU, packed b64 writes)
    int r = tid & 31, d8 = tid >> 5;          // d8: 0..7, covers dims d8*4..d8*4+3
    float4 xv = ((const float4*)x)[base + r];
    f16x4 sv, cv, pv;
    #pragma unroll
    for (int j = 0; j < 4; ++j){
      int d = d8 * 4 + j;
      float4 w = ((const float4*)pe_w)[d];
      float u = fmaf(xv.x, w.x, fmaf(xv.y, w.y, fmaf(xv.z, w.z, fmaf(xv.w, w.w, pe_b[d]))));
      sv[j] = (f16)fsin(u);
      cv[j] = (f16)fcos(u);
      float4 wp = ((const float4*)p1_w)[d];
      float z = 30.0f * fmaf(xv.x, wp.x, fmaf(xv.y, wp.y, fmaf(xv.z, wp.z, fmaf(xv.w, wp.w, p1_b[d]))));
      pv[j] = (f16)fsin(z);
    }
    *(f16x4*)(h0 + r * 72 + d8 * 4)      = sv;
    *(f16x4*)(h0 + r * 72 + 32 + d8 * 4) = cv;
    *(f16x4*)(f1 + r * 40 + d8 * 4)      = pv;
  }
  __syncthreads();   // A

  { // policy layer 2 (swapped operands): one tile per wave -> f2
    int ct = wid & 1, rt2 = wid >> 1;
    float4 bias = *(const float4*)(bws + FB_P2 + ct * 16 + lk * 4);
    f16x8 wv = *(const f16x8*)(ws + OFF_WP2 + (ct * 16 + l15) * 32 + kb);
    f16x8 a  = *(const f16x8*)(f1 + (rt2 * 16 + l15) * 40 + kb);
    f32x4 acc = {0.f, 0.f, 0.f, 0.f};
    acc = __builtin_amdgcn_mfma_f32_16x16x32_f16(wv, a, acc, 0, 0, 0);
    int r = rt2 * 16 + l15, n0 = ct * 16 + lk * 4;
    f16x4 o;
    o[0] = (f16)fsin(acc[0] + bias.x); o[1] = (f16)fsin(acc[1] + bias.y);
    o[2] = (f16)fsin(acc[2] + bias.z); o[3] = (f16)fsin(acc[3] + bias.w);
    *(f16x4*)(f2 + r * 40 + n0) = o;
  }
  // no barrier: f2 only read after barrier F; s1 below uses disjoint buffers.

  // SIREN s1: [32,64] -> [32,128], sin                (barrier B inside macro)
  MM_LAYER(64, 8, h0, 72, OFF_W1, FB_B1,
           STORE4(h1, 136, fsin(v0), fsin(v1), fsin(v2), fsin(v3)))
  // SIREN s2: [32,128] -> [32,256], sin               (barrier C)
  MM_LAYER(128, 16, h1, 136, OFF_W2, FB_B2,
           STORE4(h2, 264, fsin(v0), fsin(v1), fsin(v2), fsin(v3)))
  // fc1: [32,256] -> [32,64], relu                    (barrier D)
  MM_LAYER(256, 4, h2, 264, OFF_WF1, FB_F1,
           STORE4(t1, 72, fmaxf(v0, 0.f), fmaxf(v1, 0.f), fmaxf(v2, 0.f), fmaxf(v3, 0.f)))
  // fc2: [32,64] -> [32,64], relu                     (barrier E)
  MM_LAYER(64, 4, t1, 72, OFF_WF2, FB_F2,
           STORE4(t2, 72, fmaxf(v0, 0.f), fmaxf(v1, 0.f), fmaxf(v2, 0.f), fmaxf(v3, 0.f)))
  // fc3 + residual IN PLACE: h2 <- relu(t2@W3 + h2)   (barrier F)
  MM_LAYER(64, 16, t2, 72, OFF_WF3, FB_F3,
           f16x4 old = *(const f16x4*)(h2 + r * 264 + n0);
           STORE4(h2, 264, fmaxf(v0 + (float)old[0], 0.f), fmaxf(v1 + (float)old[1], 0.f),
                           fmaxf(v2 + (float)old[2], 0.f), fmaxf(v3 + (float)old[3], 0.f)))

  { // gate + experts fused (original orientation), softmax + routing in-wave
    if (wid < 2){
      int rt2 = wid;
      float bias = bws[FB_GE + l15];
      f32x4 acc = {0.f, 0.f, 0.f, 0.f};
      #pragma unroll
      for (int ks = 0; ks < 8; ks++){
        f16x8 a = *(const f16x8*)(h2 + (rt2 * 16 + l15) * 264 + ks * 32 + kb);
        f16x8 b = *(const f16x8*)(ws + OFF_WGE + l15 * 288 + ks * 32 + kb);
        acc = __builtin_amdgcn_mfma_f32_16x16x32_f16(a, b, acc, 0, 0, 0);
      }
      { // ks = 8: policy features from f2
        f16x8 a = *(const f16x8*)(f2 + (rt2 * 16 + l15) * 40 + kb);
        f16x8 b = *(const f16x8*)(ws + OFF_WGE + l15 * 288 + 256 + kb);
        acc = __builtin_amdgcn_mfma_f32_16x16x32_f16(a, b, acc, 0, 0, 0);
      }
      // D layout: col = l15 (0..6 logits, 8..14 preds), row = rt2*16 + lk*4 + i.
      #pragma unroll
      for (int i = 0; i < 4; i++){
        float v = acc[i] + bias;
        float pred = __shfl_xor(v, 8);          // lane e (<7) gets expert e's pred
        float lg = (l15 < 7) ? v : -1e30f;
        float m = lg;
        m = fmaxf(m, __shfl_xor(m, 1));
        m = fmaxf(m, __shfl_xor(m, 2));
        m = fmaxf(m, __shfl_xor(m, 4));
        float p = __expf(lg - m);               // lane 7: exp(-1e30 - m) = 0
        float c = p * pred;
        float s = p, y = c;
        s += __shfl_xor(s, 1); y += __shfl_xor(y, 1);
        s += __shfl_xor(s, 2); y += __shfl_xor(y, 2);
        s += __shfl_xor(s, 4); y += __shfl_xor(y, 4);
        if (l15 == 0) out[base + rt2 * 16 + lk * 4 + i] = y / s;
      }
    }
  }
}

extern "C" void kernel_launch(void* const* d_in, const int* in_sizes, int n_in,
                              void* d_out, int out_size, void* d_ws, size_t ws_size,
                              hipStream_t stream)
{
  const float* x     = (const float*)d_in[0];
  const float* pe_w  = (const float*)d_in[1];
  const float* pe_b  = (const float*)d_in[2];
  const float* s1_w  = (const float*)d_in[3];
  const float* s1_b  = (const float*)d_in[4];
  const float* s2_w  = (const float*)d_in[5];
  const float* s2_b  = (const float*)d_in[6];
  const float* fc1_w = (const float*)d_in[7];
  const float* fc1_b = (const float*)d_in[8];
  const float* fc2_w = (const float*)d_in[9];
  const float* fc2_b = (const float*)d_in[10];
  const float* fc3_w = (const float*)d_in[11];
  const float* fc3_b = (const float*)d_in[12];
  const float* p1_w  = (const float*)d_in[13];
  const float* p1_b  = (const float*)d_in[14];
  const float* p2_w  = (const float*)d_in[15];
  const float* p2_b  = (const float*)d_in[16];
  const float* gate_w= (const float*)d_in[17];
  const float* gate_b= (const float*)d_in[18];
  const float* exp_w = (const float*)d_in[19];
  const float* exp_b = (const float*)d_in[20];
  f16* ws = (f16*)d_ws;

  convert_w<<<128, 256, 0, stream>>>(s1_w, s1_b, s2_w, s2_b, fc1_w, fc1_b, fc2_w, fc2_b,
                                     fc3_w, fc3_b, gate_w, gate_b, exp_w, exp_b, p2_w, p2_b, ws);
  moe_main<<<524288 / 32, 256, 0, stream>>>(x, pe_w, pe_b, p1_w, p1_b, ws, (float*)d_out);
}

// Round 4
// 260.020 us; speedup vs baseline: 1.3257x; 1.3257x over previous
//
#include <hip/hip_runtime.h>

typedef _Float16 f16;
typedef _Float16 f16x4 __attribute__((ext_vector_type(4)));
typedef _Float16 f16x8 __attribute__((ext_vector_type(8)));
typedef float f32x4 __attribute__((ext_vector_type(4)));

// ---- f16 weight arena layout in d_ws (units: halfs) ----
#define OFF_W1  0            // s1_w *30   [128][64]
#define OFF_W2  8192         // s2_w *30   [256][128]
#define OFF_WF1 40960        // fc1_w      [64][256]
#define OFF_WF2 57344        // fc2_w      [64][64]
#define OFF_WF3 61440        // fc3_w      [256][64]
#define OFF_WGE 77824        // [16][288]: rows 0..6 gate_w, 8..14 exp_w (cols<256), rest 0
#define OFF_WP2 82432        // p2_w *30   [32][32]
#define TOTH    83456
// ---- fp32 bias arena at (float*)(ws + TOTH), units: floats ----
#define FB_B1  0             // 30*s1_b (128)
#define FB_B2  128           // 30*s2_b (256)
#define FB_F1  384           // fc1_b (64)
#define FB_F2  448           // fc2_b (64)
#define FB_F3  512           // fc3_b (256)
#define FB_GE  768           // gate_b(0..6), 0, exp_b(8..14), 0
#define FB_P2  784           // 30*p2_b (32)

__device__ __forceinline__ float sin_rev(float r){
#if __has_builtin(__builtin_amdgcn_sinf)
  return __builtin_amdgcn_sinf(r);     // v_sin_f32: input in revolutions
#else
  return __sinf(r * 6.283185307179586f);
#endif
}
__device__ __forceinline__ float fsin(float x){
  float r = x * 0.15915494309189535f;  // 1/(2pi)
  r -= rintf(r);                       // reduce to [-0.5, 0.5] rev
  return sin_rev(r);
}
__device__ __forceinline__ float fcos(float x){
  float r = x * 0.15915494309189535f + 0.25f;  // cos(x) = sin(x + pi/2)
  r -= rintf(r);
  return sin_rev(r);
}

// ---------- weight conversion: fp32 -> f16, OMEGA folded ----------
__global__ void convert_w(const float* __restrict__ s1w, const float* __restrict__ s1b,
                          const float* __restrict__ s2w, const float* __restrict__ s2b,
                          const float* __restrict__ f1w, const float* __restrict__ f1b,
                          const float* __restrict__ f2w, const float* __restrict__ f2b,
                          const float* __restrict__ f3w, const float* __restrict__ f3b,
                          const float* __restrict__ gw,  const float* __restrict__ gb,
                          const float* __restrict__ ew,  const float* __restrict__ eb,
                          const float* __restrict__ p2w, const float* __restrict__ p2b,
                          f16* __restrict__ ws)
{
  int stride = gridDim.x * blockDim.x;
  int tid0 = blockIdx.x * blockDim.x + threadIdx.x;
  for (int i = tid0; i < TOTH; i += stride){
    float v;
    if (i < OFF_W2)       v = 30.0f * s1w[i];
    else if (i < OFF_WF1) v = 30.0f * s2w[i - OFF_W2];
    else if (i < OFF_WF2) v = f1w[i - OFF_WF1];
    else if (i < OFF_WF3) v = f2w[i - OFF_WF2];
    else if (i < OFF_WGE) v = f3w[i - OFF_WF3];
    else if (i < OFF_WP2){
      int j = i - OFF_WGE; int row = j / 288; int col = j - row * 288;
      v = (row < 7) ? gw[row * 288 + col]
        : ((row >= 8 && row < 15 && col < 256) ? ew[(row - 8) * 256 + col] : 0.0f);
    }
    else v = 30.0f * p2w[i - OFF_WP2];
    ws[i] = (f16)v;
  }
  float* bws = (float*)(ws + TOTH);
  for (int i = tid0; i < 816; i += stride){
    float v;
    if (i < 128)      v = 30.0f * s1b[i];
    else if (i < 384) v = 30.0f * s2b[i - 128];
    else if (i < 448) v = f1b[i - 384];
    else if (i < 512) v = f2b[i - 448];
    else if (i < 768) v = f3b[i - 512];
    else if (i < 784){ int j = i - 768;
      v = (j < 7) ? gb[j] : ((j >= 8 && j < 15) ? eb[j - 8] : 0.0f); }
    else v = 30.0f * p2b[i - 784];
    bws[i] = v;
  }
}

// Swapped-operand layer pass over a 64-row block. Wave handles NCT_ ct-tiles
// (ct given by CTEXPR_ over jj) x NRT_ row-tiles starting at RT0_. A-frags
// hoisted per layer; weight frag loaded once per ct, reused across rt.
// Epilogue sees r (0..63), n0, v0..v3.
#define MM_LAYER(K_, ACT_, SA_, NCT_, CTEXPR_, RT0_, NRT_, WOFF_, BOFF_, ...)        \
  {                                                                                  \
    f16x8 af[NRT_][(K_) / 32];                                                       \
    _Pragma("unroll")                                                                \
    for (int rr = 0; rr < (NRT_); ++rr)                                              \
      _Pragma("unroll")                                                              \
      for (int ks = 0; ks < (K_) / 32; ++ks)                                         \
        af[rr][ks] = *(const f16x8*)((ACT_) + (((RT0_) + rr) * 16 + l15) * (SA_) + ks * 32 + kb); \
    _Pragma("unroll")                                                                \
    for (int jj = 0; jj < (NCT_); ++jj){                                             \
      const int ct = (CTEXPR_);                                                      \
      float4 bias = *(const float4*)(bws + (BOFF_) + ct * 16 + lk * 4);              \
      f32x4 acc[NRT_];                                                               \
      _Pragma("unroll")                                                              \
      for (int rr = 0; rr < (NRT_); ++rr) acc[rr] = (f32x4){0.f, 0.f, 0.f, 0.f};     \
      _Pragma("unroll")                                                              \
      for (int ks = 0; ks < (K_) / 32; ++ks){                                        \
        f16x8 wv = *(const f16x8*)(ws + (WOFF_) + (ct * 16 + l15) * (K_) + ks * 32 + kb); \
        _Pragma("unroll")                                                            \
        for (int rr = 0; rr < (NRT_); ++rr)                                          \
          acc[rr] = __builtin_amdgcn_mfma_f32_16x16x32_f16(wv, af[rr][ks], acc[rr], 0, 0, 0); \
      }                                                                              \
      _Pragma("unroll")                                                              \
      for (int rr = 0; rr < (NRT_); ++rr){                                           \
        const int r = ((RT0_) + rr) * 16 + l15;                                      \
        const int n0 = ct * 16 + lk * 4;                                             \
        float v0 = acc[rr][0] + bias.x, v1 = acc[rr][1] + bias.y,                    \
              v2 = acc[rr][2] + bias.z, v3 = acc[rr][3] + bias.w;                    \
        __VA_ARGS__;                                                                 \
      }                                                                              \
    }                                                                                \
  }                                                                                  \
  __syncthreads();

#define STORE4(P_, S_, E0_, E1_, E2_, E3_)                                           \
  { f16x4 o; o[0] = (f16)(E0_); o[1] = (f16)(E1_); o[2] = (f16)(E2_); o[3] = (f16)(E3_); \
    *(f16x4*)((P_) + r * (S_) + n0) = o; }

__global__ __launch_bounds__(512, 4) void moe_main(
    const float* __restrict__ x,
    const float* __restrict__ pe_w, const float* __restrict__ pe_b,
    const float* __restrict__ p1_w, const float* __restrict__ p1_b,
    const f16* __restrict__ ws, float* __restrict__ out)
{
  const float* bws = (const float*)(ws + TOTH);
  __shared__ __align__(16) unsigned char smem[65536];
  f16* h0 = (f16*)smem;                  // [64][72]  PE out; overlay t1 [64][72]
  f16* t1 = (f16*)smem;
  f16* h1 = (f16*)(smem + 9216);         // [64][136] s1 out; overlay t2 [64][136]
  f16* t2 = (f16*)(smem + 9216);
  f16* h2 = (f16*)(smem + 26624);        // [64][264] s2 out; fc3 in-place; f1 overlay
  f16* f1 = (f16*)(smem + 26624);        // [64][40]  policy layer-1 (dead before s2)
  f16* f2 = (f16*)(smem + 60416);        // [64][40]  policy layer-2 out

  const int tid = threadIdx.x;
  const int lane = tid & 63, wid = tid >> 6;
  const int l15 = lane & 15, lk = lane >> 4, kb = lk * 8;
  const long long base = (long long)blockIdx.x * 64;

  { // positional encoding (sin/cos) + policy layer 1  (fp32 VALU, packed b64 writes)
    int r = lane, d8 = wid;              // row = lane (0..63), dims d8*4 .. d8*4+3
    float4 xv = ((const float4*)x)[base + r];
    f16x4 sv, cv, pv;
    #pragma unroll
    for (int j = 0; j < 4; ++j){
      int d = d8 * 4 + j;
      float4 w = ((const float4*)pe_w)[d];
      float u = fmaf(xv.x, w.x, fmaf(xv.y, w.y, fmaf(xv.z, w.z, fmaf(xv.w, w.w, pe_b[d]))));
      sv[j] = (f16)fsin(u);
      cv[j] = (f16)fcos(u);
      float4 wp = ((const float4*)p1_w)[d];
      float z = 30.0f * fmaf(xv.x, wp.x, fmaf(xv.y, wp.y, fmaf(xv.z, wp.z, fmaf(xv.w, wp.w, p1_b[d]))));
      pv[j] = (f16)fsin(z);
    }
    *(f16x4*)(h0 + r * 72 + d8 * 4)      = sv;
    *(f16x4*)(h0 + r * 72 + 32 + d8 * 4) = cv;
    *(f16x4*)(f1 + r * 40 + d8 * 4)      = pv;
  }
  __syncthreads();   // A

  { // policy layer 2 (swapped): 8 tiles = 2ct x 4rt, one per wave -> f2
    int ct = wid & 1, rt2 = wid >> 1;
    float4 bias = *(const float4*)(bws + FB_P2 + ct * 16 + lk * 4);
    f16x8 wv = *(const f16x8*)(ws + OFF_WP2 + (ct * 16 + l15) * 32 + kb);
    f16x8 a  = *(const f16x8*)(f1 + (rt2 * 16 + l15) * 40 + kb);
    f32x4 acc = {0.f, 0.f, 0.f, 0.f};
    acc = __builtin_amdgcn_mfma_f32_16x16x32_f16(wv, a, acc, 0, 0, 0);
    int r = rt2 * 16 + l15, n0 = ct * 16 + lk * 4;
    f16x4 o;
    o[0] = (f16)fsin(acc[0] + bias.x); o[1] = (f16)fsin(acc[1] + bias.y);
    o[2] = (f16)fsin(acc[2] + bias.z); o[3] = (f16)fsin(acc[3] + bias.w);
    *(f16x4*)(f2 + r * 40 + n0) = o;
  }
  // no barrier: f2 only read at gate; s1 below reads h0 / writes h1 (disjoint).

  // SIREN s1: [64,64] -> [64,128], sin      ct = wid (8 tiles), rt 0..3  (barrier B)
  MM_LAYER(64, h0, 72, 1, wid, 0, 4, OFF_W1, FB_B1,
           STORE4(h1, 136, fsin(v0), fsin(v1), fsin(v2), fsin(v3)))
  // SIREN s2: [64,128] -> [64,256], sin     ct = {wid, wid+8}, rt 0..3   (barrier C)
  MM_LAYER(128, h1, 136, 2, (wid + jj * 8), 0, 4, OFF_W2, FB_B2,
           STORE4(h2, 264, fsin(v0), fsin(v1), fsin(v2), fsin(v3)))
  // fc1: [64,256] -> [64,64], relu          ct = wid&3, rt-pair = wid>>2 (barrier D)
  MM_LAYER(256, h2, 264, 1, (wid & 3), (wid >> 2) * 2, 2, OFF_WF1, FB_F1,
           STORE4(t1, 72, fmaxf(v0, 0.f), fmaxf(v1, 0.f), fmaxf(v2, 0.f), fmaxf(v3, 0.f)))
  // fc2: [64,64] -> [64,64], relu                                        (barrier E)
  MM_LAYER(64, t1, 72, 1, (wid & 3), (wid >> 2) * 2, 2, OFF_WF2, FB_F2,
           STORE4(t2, 136, fmaxf(v0, 0.f), fmaxf(v1, 0.f), fmaxf(v2, 0.f), fmaxf(v3, 0.f)))
  // fc3 + residual IN PLACE: h2 <- relu(t2@W3 + h2)                      (barrier F)
  MM_LAYER(64, t2, 136, 2, (wid + jj * 8), 0, 4, OFF_WF3, FB_F3,
           f16x4 old = *(const f16x4*)(h2 + r * 264 + n0);
           STORE4(h2, 264, fmaxf(v0 + (float)old[0], 0.f), fmaxf(v1 + (float)old[1], 0.f),
                           fmaxf(v2 + (float)old[2], 0.f), fmaxf(v3 + (float)old[3], 0.f)))

  { // gate + experts fused (A = activations), softmax + routing in-wave
    if (wid < 4){
      int rt4 = wid;                       // rows rt4*16 .. rt4*16+15
      float bias = bws[FB_GE + l15];
      f32x4 acc = {0.f, 0.f, 0.f, 0.f};
      #pragma unroll
      for (int ks = 0; ks < 8; ks++){
        f16x8 a = *(const f16x8*)(h2 + (rt4 * 16 + l15) * 264 + ks * 32 + kb);
        f16x8 b = *(const f16x8*)(ws + OFF_WGE + l15 * 288 + ks * 32 + kb);
        acc = __builtin_amdgcn_mfma_f32_16x16x32_f16(a, b, acc, 0, 0, 0);
      }
      { // ks = 8: policy features from f2
        f16x8 a = *(const f16x8*)(f2 + (rt4 * 16 + l15) * 40 + kb);
        f16x8 b = *(const f16x8*)(ws + OFF_WGE + l15 * 288 + 256 + kb);
        acc = __builtin_amdgcn_mfma_f32_16x16x32_f16(a, b, acc, 0, 0, 0);
      }
      // D layout: col = l15 (0..6 logits, 8..14 preds), row = rt4*16 + lk*4 + i.
      #pragma unroll
      for (int i = 0; i < 4; i++){
        float v = acc[i] + bias;
        float pred = __shfl_xor(v, 8);          // lane e (<7) gets expert e's pred
        float lg = (l15 < 7) ? v : -1e30f;
        float m = lg;
        m = fmaxf(m, __shfl_xor(m, 1));
        m = fmaxf(m, __shfl_xor(m, 2));
        m = fmaxf(m, __shfl_xor(m, 4));
        float p = __expf(lg - m);               // lane 7: exp(-1e30 - m) = 0
        float c = p * pred;
        float s = p, y = c;
        s += __shfl_xor(s, 1); y += __shfl_xor(y, 1);
        s += __shfl_xor(s, 2); y += __shfl_xor(y, 2);
        s += __shfl_xor(s, 4); y += __shfl_xor(y, 4);
        if (l15 == 0) out[base + rt4 * 16 + lk * 4 + i] = y / s;
      }
    }
  }
}

extern "C" void kernel_launch(void* const* d_in, const int* in_sizes, int n_in,
                              void* d_out, int out_size, void* d_ws, size_t ws_size,
                              hipStream_t stream)
{
  const float* x     = (const float*)d_in[0];
  const float* pe_w  = (const float*)d_in[1];
  const float* pe_b  = (const float*)d_in[2];
  const float* s1_w  = (const float*)d_in[3];
  const float* s1_b  = (const float*)d_in[4];
  const float* s2_w  = (const float*)d_in[5];
  const float* s2_b  = (const float*)d_in[6];
  const float* fc1_w = (const float*)d_in[7];
  const float* fc1_b = (const float*)d_in[8];
  const float* fc2_w = (const float*)d_in[9];
  const float* fc2_b = (const float*)d_in[10];
  const float* fc3_w = (const float*)d_in[11];
  const float* fc3_b = (const float*)d_in[12];
  const float* p1_w  = (const float*)d_in[13];
  const float* p1_b  = (const float*)d_in[14];
  const float* p2_w  = (const float*)d_in[15];
  const float* p2_b  = (const float*)d_in[16];
  const float* gate_w= (const float*)d_in[17];
  const float* gate_b= (const float*)d_in[18];
  const float* exp_w = (const float*)d_in[19];
  const float* exp_b = (const float*)d_in[20];
  f16* ws = (f16*)d_ws;

  convert_w<<<128, 256, 0, stream>>>(s1_w, s1_b, s2_w, s2_b, fc1_w, fc1_b, fc2_w, fc2_b,
                                     fc3_w, fc3_b, gate_w, gate_b, exp_w, exp_b, p2_w, p2_b, ws);
  moe_main<<<524288 / 64, 512, 0, stream>>>(x, pe_w, pe_b, p1_w, p1_b, ws, (float*)d_out);
}